// Round 5
// baseline (561.347 us; speedup 1.0000x reference)
//
#include <hip/hip_runtime.h>

using bf16x8 = __attribute__((ext_vector_type(8))) short;
using f32x4  = __attribute__((ext_vector_type(4))) float;

static constexpr int NB = 8;
static constexpr int NS = 4096;
static constexpr int NH = 16;
static constexpr int ND = 128;
static constexpr int BH = NB * NH;   // 128
static constexpr int HD = NH * ND;   // 2048

// round-to-nearest-even pack of two fp32 -> bf16x2 in a uint32
__device__ inline unsigned pack2(float a, float b) {
    unsigned ua = __float_as_uint(a), ub = __float_as_uint(b);
    ua += 0x7fffu + ((ua >> 16) & 1u);
    ub += 0x7fffu + ((ub >> 16) & 1u);
    return (ua >> 16) | (ub & 0xffff0000u);
}

__device__ inline int swzh(int row) { return (row ^ (row >> 2)) & 7; }

// pure-register: exp+pack one tile's worth of per-thread data (4 d x 8 s)
__device__ inline void pack_tile(const float4* kq, const float4* vq,
                                 float dsum[4], uint4 pa[4], uint4 pb[4]) {
    const float* kf = (const float*)kq;
    const float* vf = (const float*)vq;
#pragma unroll
    for (int i = 0; i < 4; ++i) {
        float e[8];
#pragma unroll
        for (int j = 0; j < 8; ++j) {
            e[j] = __expf(kf[4 * j + i]);
            dsum[i] += e[j];
        }
        pa[i] = make_uint4(pack2(e[0], e[1]), pack2(e[2], e[3]),
                           pack2(e[4], e[5]), pack2(e[6], e[7]));
        pb[i] = make_uint4(pack2(vf[0 + i], vf[4 + i]),
                           pack2(vf[8 + i], vf[12 + i]),
                           pack2(vf[16 + i], vf[20 + i]),
                           pack2(vf[24 + i], vf[28 + i]));
    }
}

// ---------------------------------------------------------------------------
// Kernel 1: per (b,h,S-chunk): pctx_t[e][d] = sum_s exp(k[s,d]) * v[s,e]
// (TRANSPOSED, fp32) + pden[d] = sum_s exp(k[s,d]).
// T14 structure: single 32KB LDS buffer; next tile's global loads issued into
// a second register set BEFORE the current tile is consumed, so the vmcnt
// wait is covered by pack+barriers+MFMA of the current tile. NC=8 + 3 blocks/CU.
// ---------------------------------------------------------------------------
template <int NC>
__global__ __launch_bounds__(256, 3)
void ctx_mfma(const float* __restrict__ kk, const float* __restrict__ vv,
              float* __restrict__ pctx_t, float* __restrict__ pden) {
    constexpr int SC = NS / NC;
    constexpr int T  = SC / 64;            // even for all NC in {1,2,4,8,16}
    __shared__ __align__(16) unsigned short aL[128][64];  // exp(k)^T tile
    __shared__ __align__(16) unsigned short bL[128][64];  // v^T tile

    const int blk = blockIdx.x, bh = blk / NC, c = blk % NC;
    const int b = bh >> 4, h = bh & 15;
    const int tid = threadIdx.x, lane = tid & 63, wv = tid >> 6;
    const int r15 = lane & 15, hi = lane >> 4;
    const size_t base = (size_t)b * NS * HD + (size_t)h * ND;

    const int d0 = (tid & 31) * 4;   // 4 consecutive d per thread
    const int sg = tid >> 5;         // s-chunk 0..7 (8 s each)

    float dsum[4] = {0.f, 0.f, 0.f, 0.f};

    auto issue = [&](int t, float4* kq, float4* vq) {
        const size_t s0 = (size_t)(c * SC + t * 64 + 8 * sg);
        const float* kp = kk + base + s0 * HD + d0;
        const float* vp = vv + base + s0 * HD + d0;
#pragma unroll
        for (int j = 0; j < 8; ++j) kq[j] = *(const float4*)(kp + (size_t)j * HD);
#pragma unroll
        for (int j = 0; j < 8; ++j) vq[j] = *(const float4*)(vp + (size_t)j * HD);
    };

    auto store_tile = [&](const uint4* pa, const uint4* pb) {
#pragma unroll
        for (int i = 0; i < 4; ++i) {
            const int row = d0 + i;
            const int cw = sg ^ swzh(row);
            *(uint4*)&aL[row][cw * 8] = pa[i];
            *(uint4*)&bL[row][cw * 8] = pb[i];
        }
    };

    f32x4 acc[4][4];
#pragma unroll
    for (int m = 0; m < 4; ++m)
#pragma unroll
        for (int n = 0; n < 4; ++n) acc[m][n] = (f32x4){0.f, 0.f, 0.f, 0.f};

    const int wd = wv >> 1, we = wv & 1;        // wave's 64x64 quadrant

    auto mma = [&]() {
#pragma unroll
        for (int ks = 0; ks < 2; ++ks) {
            bf16x8 af[4], bfv[4];
#pragma unroll
            for (int m = 0; m < 4; ++m) {
                const int row = 64 * wd + 16 * m + r15;
                const int cw = (4 * ks + hi) ^ swzh(row);
                af[m] = *(const bf16x8*)&aL[row][cw * 8];
            }
#pragma unroll
            for (int n = 0; n < 4; ++n) {
                const int row = 64 * we + 16 * n + r15;
                const int cw = (4 * ks + hi) ^ swzh(row);
                bfv[n] = *(const bf16x8*)&bL[row][cw * 8];
            }
#pragma unroll
            for (int m = 0; m < 4; ++m)
#pragma unroll
                for (int n = 0; n < 4; ++n)
                    acc[m][n] = __builtin_amdgcn_mfma_f32_16x16x32_bf16(
                        af[m], bfv[n], acc[m][n], 0, 0, 0);
        }
    };

    float4 ka[8], va[8], kb[8], vb[8];
    issue(0, ka, va);

    for (int t = 0; t < T; t += 2) {
        // ---- tile t (register set A), prefetch t+1 into B ----
        if (t + 1 < T) issue(t + 1, kb, vb);
        {
            uint4 pa[4], pb[4];
            pack_tile(ka, va, dsum, pa, pb);   // waits only on A's loads
            __syncthreads();                   // all waves done reading LDS
            store_tile(pa, pb);
            __syncthreads();                   // tile staged
            mma();
        }
        // ---- tile t+1 (register set B), prefetch t+2 into A ----
        if (t + 2 < T) issue(t + 2, ka, va);
        {
            uint4 pa[4], pb[4];
            pack_tile(kb, vb, dsum, pa, pb);
            __syncthreads();
            store_tile(pa, pb);
            __syncthreads();
            mma();
        }
    }

    // denominator: per-d partials over this thread's 8 s columns
    __syncthreads();
    float* dr = (float*)&aL[0][0];             // 8 x 128 floats = 4 KB
    *(float4*)&dr[sg * 128 + d0] = make_float4(dsum[0], dsum[1], dsum[2], dsum[3]);
    __syncthreads();
    if (tid < 128) {
        float s = 0.f;
#pragma unroll
        for (int r = 0; r < 8; ++r) s += dr[r * 128 + tid];
        pden[(size_t)blk * 128 + tid] = s;
    }

    // write transposed partial context: pctx_t[e][d], float4 along d
    float* po = pctx_t + (size_t)blk * (ND * ND);
#pragma unroll
    for (int m = 0; m < 4; ++m)
#pragma unroll
        for (int n = 0; n < 4; ++n) {
            const int e  = 64 * we + 16 * n + r15;
            const int dd = 64 * wd + 16 * m + 4 * hi;
            *(f32x4*)&po[e * ND + dd] = acc[m][n];
        }
}

// ---------------------------------------------------------------------------
// Kernel 2: sum chunk partials, normalize, emit bf16 ctx_t[e][d]
// ---------------------------------------------------------------------------
__global__ void ctx_combine(const float* __restrict__ pctx_t,
                            const float* __restrict__ pden,
                            unsigned short* __restrict__ ctx_t, int nc) {
    const int gid = blockIdx.x * 256 + threadIdx.x;      // over BH*16384/2
    const size_t w = (size_t)gid * 2;
    const int bh = (int)(w >> 14);
    const int wi = (int)(w & 16383);
    const int dd = wi & 127;
    float s0 = 0.f, s1 = 0.f, dn0 = 0.f, dn1 = 0.f;
    for (int c2 = 0; c2 < nc; ++c2) {
        const float* p  = pctx_t + (((size_t)(bh * nc + c2)) << 14) + wi;
        const float* pd = pden + (size_t)(bh * nc + c2) * ND + dd;
        s0 += p[0]; s1 += p[1];
        dn0 += pd[0]; dn1 += pd[1];
    }
    *(unsigned*)&ctx_t[w] = pack2(s0 / dn0, s1 / dn1);
}

// ---------------------------------------------------------------------------
// Kernel 3: out[s][e] = (1/sum_d exp(q[s,d])) * sum_d exp(q[s,d]) * ctx[d][e]
// ---------------------------------------------------------------------------
__global__ __launch_bounds__(256, 2)
void out_mfma(const float* __restrict__ qq,
              const unsigned short* __restrict__ ctx_t,
              float* __restrict__ out) {
    __shared__ __align__(16) unsigned short cL[128][128];    // 32KB ctx_t
    __shared__ __align__(16) unsigned short qL[2][32][128];  // 16KB q tiles
    __shared__ float qd[2][32];

    const int blk = blockIdx.x, bh = blk >> 3, c = blk & 7;
    const int b = bh >> 4, h = bh & 15;
    const int tid = threadIdx.x, lane = tid & 63, wv = tid >> 6;
    const int r15 = lane & 15, hi = lane >> 4;

    // stage ctx_t -> LDS (swizzled: chunk ^ (row&15)); 2048 uint4 total
    {
        const unsigned short* src = ctx_t + ((size_t)bh << 14);
#pragma unroll
        for (int j = 0; j < 8; ++j) {
            const int g = tid + 256 * j;
            const int e = g >> 4, cs = g & 15;
            uint4 t4 = *(const uint4*)&src[e * 128 + cs * 8];
            *(uint4*)&cL[e][(cs ^ (e & 15)) * 8] = t4;
        }
    }

    const size_t qbase = (size_t)b * NS * HD + (size_t)h * ND;
    const int s_blk = c * 512;

    auto stageq = [&](int t, int buf) {
#pragma unroll
        for (int jj = 0; jj < 2; ++jj) {
            const int g = tid + 256 * jj;
            const int s = g >> 4, cs = g & 15;
            const float* qp = qq + qbase + (size_t)(s_blk + t * 32 + s) * HD + cs * 8;
            float x[8];
            *(float4*)&x[0] = *(const float4*)qp;
            *(float4*)&x[4] = *(const float4*)(qp + 4);
            float ps = 0.f;
            unsigned pw[4];
#pragma unroll
            for (int j2 = 0; j2 < 4; ++j2) {
                float e0 = __expf(x[2 * j2]), e1 = __expf(x[2 * j2 + 1]);
                ps += e0 + e1;
                pw[j2] = pack2(e0, e1);
            }
            ps += __shfl_xor(ps, 1);
            ps += __shfl_xor(ps, 2);
            ps += __shfl_xor(ps, 4);
            ps += __shfl_xor(ps, 8);            // row-sum across the 16 d-chunks
            *(uint4*)&qL[buf][s][(cs ^ (s & 15)) * 8] =
                make_uint4(pw[0], pw[1], pw[2], pw[3]);
            if ((lane & 15) == 0) qd[buf][s] = ps;
        }
    };

    __syncthreads();                             // ctx staged

    // hoist B fragments: wave w covers e in [32w, 32w+32)
    bf16x8 bfr[2][4];
#pragma unroll
    for (int n = 0; n < 2; ++n) {
        const int e = 32 * wv + 16 * n + r15;
#pragma unroll
        for (int ks = 0; ks < 4; ++ks) {
            const int cw = (4 * ks + hi) ^ (e & 15);
            bfr[n][ks] = *(const bf16x8*)&cL[e][cw * 8];
        }
    }

    stageq(0, 0);
    for (int t = 0; t < 16; ++t) {
        __syncthreads();
        if (t + 1 < 16) stageq(t + 1, (t + 1) & 1);
        const int buf = t & 1;

        f32x4 acc[2][2];
#pragma unroll
        for (int m = 0; m < 2; ++m)
#pragma unroll
            for (int n = 0; n < 2; ++n) acc[m][n] = (f32x4){0.f, 0.f, 0.f, 0.f};

#pragma unroll
        for (int ks = 0; ks < 4; ++ks) {
            bf16x8 af[2];
#pragma unroll
            for (int m = 0; m < 2; ++m) {
                const int s = 16 * m + r15;
                const int cw = (4 * ks + hi) ^ (s & 15);
                af[m] = *(const bf16x8*)&qL[buf][s][cw * 8];
            }
#pragma unroll
            for (int m = 0; m < 2; ++m)
#pragma unroll
                for (int n = 0; n < 2; ++n)
                    acc[m][n] = __builtin_amdgcn_mfma_f32_16x16x32_bf16(
                        af[m], bfr[n][ks], acc[m][n], 0, 0, 0);
        }

        // normalize + write
#pragma unroll
        for (int m = 0; m < 2; ++m) {
            const int sl0 = 16 * m + 4 * hi;
            const float i0 = 1.f / qd[buf][sl0];
            const float i1 = 1.f / qd[buf][sl0 + 1];
            const float i2 = 1.f / qd[buf][sl0 + 2];
            const float i3 = 1.f / qd[buf][sl0 + 3];
            const int srow = s_blk + t * 32 + sl0;
            float* ob = out + ((size_t)b * NS + srow) * HD + (size_t)h * ND;
#pragma unroll
            for (int n = 0; n < 2; ++n) {
                const int e = 32 * wv + 16 * n + r15;
                ob[0 * HD + e] = acc[m][n][0] * i0;
                ob[1 * HD + e] = acc[m][n][1] * i1;
                ob[2 * HD + e] = acc[m][n][2] * i2;
                ob[3 * HD + e] = acc[m][n][3] * i3;
            }
        }
    }
}

// ---------------------------------------------------------------------------
extern "C" void kernel_launch(void* const* d_in, const int* in_sizes, int n_in,
                              void* d_out, int out_size, void* d_ws, size_t ws_size,
                              hipStream_t stream) {
    (void)in_sizes; (void)n_in; (void)out_size;
    const float* q = (const float*)d_in[0];
    const float* k = (const float*)d_in[1];
    const float* v = (const float*)d_in[2];
    float* out = (float*)d_out;

    auto need = [](size_t nc) -> size_t {
        return 4ull * ((size_t)BH * nc * ND * ND + (size_t)BH * nc * ND) +
               2ull * (size_t)BH * ND * ND;
    };
    const int nc = (ws_size >= need(8)) ? 8
                 : (ws_size >= need(4)) ? 4
                 : (ws_size >= need(2)) ? 2 : 1;

    float* pctx_t = (float*)d_ws;
    float* pden   = pctx_t + (size_t)BH * nc * ND * ND;
    unsigned short* ctx_t = (unsigned short*)(pden + (size_t)BH * nc * ND);

    if (nc == 8)
        ctx_mfma<8><<<BH * 8, 256, 0, stream>>>(k, v, pctx_t, pden);
    else if (nc == 4)
        ctx_mfma<4><<<BH * 4, 256, 0, stream>>>(k, v, pctx_t, pden);
    else if (nc == 2)
        ctx_mfma<2><<<BH * 2, 256, 0, stream>>>(k, v, pctx_t, pden);
    else
        ctx_mfma<1><<<BH * 1, 256, 0, stream>>>(k, v, pctx_t, pden);

    ctx_combine<<<(BH * ND * ND / 2) / 256, 256, 0, stream>>>(pctx_t, pden, ctx_t, nc);

    out_mfma<<<BH * 8, 256, 0, stream>>>(q, ctx_t, out);
}

// Round 6
// 263.132 us; speedup vs baseline: 2.1333x; 2.1333x over previous
//
#include <hip/hip_runtime.h>

using bf16x8 = __attribute__((ext_vector_type(8))) short;
using f32x4  = __attribute__((ext_vector_type(4))) float;

static constexpr int NB = 8;
static constexpr int NS = 4096;
static constexpr int NH = 16;
static constexpr int ND = 128;
static constexpr int BH = NB * NH;   // 128
static constexpr int HD = NH * ND;   // 2048

// round-to-nearest-even pack of two fp32 -> bf16x2 in a uint32
__device__ inline unsigned pack2(float a, float b) {
    unsigned ua = __float_as_uint(a), ub = __float_as_uint(b);
    ua += 0x7fffu + ((ua >> 16) & 1u);
    ub += 0x7fffu + ((ub >> 16) & 1u);
    return (ua >> 16) | (ub & 0xffff0000u);
}

__device__ inline int swzh(int row) { return (row ^ (row >> 2)) & 7; }

// pure-register: exp+pack one tile's worth of per-thread data (4 d x 8 s)
__device__ inline void pack_tile(const float4* kq, const float4* vq,
                                 float dsum[4], uint4 pa[4], uint4 pb[4]) {
    const float* kf = (const float*)kq;
    const float* vf = (const float*)vq;
#pragma unroll
    for (int i = 0; i < 4; ++i) {
        float e[8];
#pragma unroll
        for (int j = 0; j < 8; ++j) {
            e[j] = __expf(kf[4 * j + i]);
            dsum[i] += e[j];
        }
        pa[i] = make_uint4(pack2(e[0], e[1]), pack2(e[2], e[3]),
                           pack2(e[4], e[5]), pack2(e[6], e[7]));
        pb[i] = make_uint4(pack2(vf[0 + i], vf[4 + i]),
                           pack2(vf[8 + i], vf[12 + i]),
                           pack2(vf[16 + i], vf[20 + i]),
                           pack2(vf[24 + i], vf[28 + i]));
    }
}

// ---------------------------------------------------------------------------
// Kernel 1: per (b,h,S-chunk): pctx_t[e][d] = sum_s exp(k[s,d]) * v[s,e]
// (TRANSPOSED, fp32) + pden[d] = sum_s exp(k[s,d]).
// LDS double-buffer + ONE register set, issue-early, single barrier per tile:
//   pack(t)[vmcnt] -> issue(t+1) -> store buf[t&1] -> sync -> mma(buf[t&1])
// store(t) vs mma(t-2) (last reader of buf[t&1]) is fenced by sync(t-1).
// ---------------------------------------------------------------------------
template <int NC>
__global__ __launch_bounds__(256, 2)
void ctx_mfma(const float* __restrict__ kk, const float* __restrict__ vv,
              float* __restrict__ pctx_t, float* __restrict__ pden) {
    constexpr int SC = NS / NC;
    constexpr int T  = SC / 64;
    __shared__ __align__(16) unsigned short aL[2][128][64];  // exp(k)^T tiles
    __shared__ __align__(16) unsigned short bL[2][128][64];  // v^T tiles

    const int blk = blockIdx.x, bh = blk / NC, c = blk % NC;
    const int b = bh >> 4, h = bh & 15;
    const int tid = threadIdx.x, lane = tid & 63, wv = tid >> 6;
    const int r15 = lane & 15, hi = lane >> 4;
    const size_t base = (size_t)b * NS * HD + (size_t)h * ND;

    const int d0 = (tid & 31) * 4;   // 4 consecutive d per thread
    const int sg = tid >> 5;         // s-chunk 0..7 (8 s each)

    float dsum[4] = {0.f, 0.f, 0.f, 0.f};

    auto issue = [&](int t, float4* kq, float4* vq) {
        const size_t s0 = (size_t)(c * SC + t * 64 + 8 * sg);
        const float* kp = kk + base + s0 * HD + d0;
        const float* vp = vv + base + s0 * HD + d0;
#pragma unroll
        for (int j = 0; j < 8; ++j) kq[j] = *(const float4*)(kp + (size_t)j * HD);
#pragma unroll
        for (int j = 0; j < 8; ++j) vq[j] = *(const float4*)(vp + (size_t)j * HD);
    };

    auto store_tile = [&](int buf, const uint4* pa, const uint4* pb) {
#pragma unroll
        for (int i = 0; i < 4; ++i) {
            const int row = d0 + i;
            const int cw = sg ^ swzh(row);
            *(uint4*)&aL[buf][row][cw * 8] = pa[i];
            *(uint4*)&bL[buf][row][cw * 8] = pb[i];
        }
    };

    f32x4 acc[4][4];
#pragma unroll
    for (int m = 0; m < 4; ++m)
#pragma unroll
        for (int n = 0; n < 4; ++n) acc[m][n] = (f32x4){0.f, 0.f, 0.f, 0.f};

    const int wd = wv >> 1, we = wv & 1;        // wave's 64x64 quadrant

    auto mma = [&](int buf) {
#pragma unroll
        for (int ks = 0; ks < 2; ++ks) {
            bf16x8 af[4], bfv[4];
#pragma unroll
            for (int m = 0; m < 4; ++m) {
                const int row = 64 * wd + 16 * m + r15;
                const int cw = (4 * ks + hi) ^ swzh(row);
                af[m] = *(const bf16x8*)&aL[buf][row][cw * 8];
            }
#pragma unroll
            for (int n = 0; n < 4; ++n) {
                const int row = 64 * we + 16 * n + r15;
                const int cw = (4 * ks + hi) ^ swzh(row);
                bfv[n] = *(const bf16x8*)&bL[buf][row][cw * 8];
            }
#pragma unroll
            for (int m = 0; m < 4; ++m)
#pragma unroll
                for (int n = 0; n < 4; ++n)
                    acc[m][n] = __builtin_amdgcn_mfma_f32_16x16x32_bf16(
                        af[m], bfv[n], acc[m][n], 0, 0, 0);
        }
    };

    float4 kq[8], vq[8];
    issue(0, kq, vq);

    for (int t = 0; t < T; ++t) {
        uint4 pa[4], pb[4];
        pack_tile(kq, vq, dsum, pa, pb);   // vmcnt wait on tile t's loads
        if (t + 1 < T) issue(t + 1, kq, vq); // next loads fly over store+sync+mma
        store_tile(t & 1, pa, pb);
        __syncthreads();                   // tile t staged (and buf free per above)
        mma(t & 1);
    }

    // denominator: per-d partials over this thread's 8 s columns
    __syncthreads();
    float* dr = (float*)&aL[0][0][0];      // 8 x 128 floats = 4 KB
    *(float4*)&dr[sg * 128 + d0] = make_float4(dsum[0], dsum[1], dsum[2], dsum[3]);
    __syncthreads();
    if (tid < 128) {
        float s = 0.f;
#pragma unroll
        for (int r = 0; r < 8; ++r) s += dr[r * 128 + tid];
        pden[(size_t)blk * 128 + tid] = s;
    }

    // write transposed partial context: pctx_t[e][d], float4 along d
    float* po = pctx_t + (size_t)blk * (ND * ND);
#pragma unroll
    for (int m = 0; m < 4; ++m)
#pragma unroll
        for (int n = 0; n < 4; ++n) {
            const int e  = 64 * we + 16 * n + r15;
            const int dd = 64 * wd + 16 * m + 4 * hi;
            *(f32x4*)&po[e * ND + dd] = acc[m][n];
        }
}

// ---------------------------------------------------------------------------
// Kernel 2: sum chunk partials, normalize, emit bf16 ctx_t[e][d]
// ---------------------------------------------------------------------------
__global__ void ctx_combine(const float* __restrict__ pctx_t,
                            const float* __restrict__ pden,
                            unsigned short* __restrict__ ctx_t, int nc) {
    const int gid = blockIdx.x * 256 + threadIdx.x;      // over BH*16384/2
    const size_t w = (size_t)gid * 2;
    const int bh = (int)(w >> 14);
    const int wi = (int)(w & 16383);
    const int dd = wi & 127;
    float s0 = 0.f, s1 = 0.f, dn0 = 0.f, dn1 = 0.f;
    for (int c2 = 0; c2 < nc; ++c2) {
        const float* p  = pctx_t + (((size_t)(bh * nc + c2)) << 14) + wi;
        const float* pd = pden + (size_t)(bh * nc + c2) * ND + dd;
        s0 += p[0]; s1 += p[1];
        dn0 += pd[0]; dn1 += pd[1];
    }
    *(unsigned*)&ctx_t[w] = pack2(s0 / dn0, s1 / dn1);
}

// ---------------------------------------------------------------------------
// Kernel 3: out[s][e] = (1/sum_d exp(q[s,d])) * sum_d exp(q[s,d]) * ctx[d][e]
// ---------------------------------------------------------------------------
__global__ __launch_bounds__(256, 2)
void out_mfma(const float* __restrict__ qq,
              const unsigned short* __restrict__ ctx_t,
              float* __restrict__ out) {
    __shared__ __align__(16) unsigned short cL[128][128];    // 32KB ctx_t
    __shared__ __align__(16) unsigned short qL[2][32][128];  // 16KB q tiles
    __shared__ float qd[2][32];

    const int blk = blockIdx.x, bh = blk >> 3, c = blk & 7;
    const int b = bh >> 4, h = bh & 15;
    const int tid = threadIdx.x, lane = tid & 63, wv = tid >> 6;
    const int r15 = lane & 15, hi = lane >> 4;

    // stage ctx_t -> LDS (swizzled: chunk ^ (row&15)); 2048 uint4 total
    {
        const unsigned short* src = ctx_t + ((size_t)bh << 14);
#pragma unroll
        for (int j = 0; j < 8; ++j) {
            const int g = tid + 256 * j;
            const int e = g >> 4, cs = g & 15;
            uint4 t4 = *(const uint4*)&src[e * 128 + cs * 8];
            *(uint4*)&cL[e][(cs ^ (e & 15)) * 8] = t4;
        }
    }

    const size_t qbase = (size_t)b * NS * HD + (size_t)h * ND;
    const int s_blk = c * 512;

    auto stageq = [&](int t, int buf) {
#pragma unroll
        for (int jj = 0; jj < 2; ++jj) {
            const int g = tid + 256 * jj;
            const int s = g >> 4, cs = g & 15;
            const float* qp = qq + qbase + (size_t)(s_blk + t * 32 + s) * HD + cs * 8;
            float x[8];
            *(float4*)&x[0] = *(const float4*)qp;
            *(float4*)&x[4] = *(const float4*)(qp + 4);
            float ps = 0.f;
            unsigned pw[4];
#pragma unroll
            for (int j2 = 0; j2 < 4; ++j2) {
                float e0 = __expf(x[2 * j2]), e1 = __expf(x[2 * j2 + 1]);
                ps += e0 + e1;
                pw[j2] = pack2(e0, e1);
            }
            ps += __shfl_xor(ps, 1);
            ps += __shfl_xor(ps, 2);
            ps += __shfl_xor(ps, 4);
            ps += __shfl_xor(ps, 8);            // row-sum across the 16 d-chunks
            *(uint4*)&qL[buf][s][(cs ^ (s & 15)) * 8] =
                make_uint4(pw[0], pw[1], pw[2], pw[3]);
            if ((lane & 15) == 0) qd[buf][s] = ps;
        }
    };

    __syncthreads();                             // ctx staged

    // hoist B fragments: wave w covers e in [32w, 32w+32)
    bf16x8 bfr[2][4];
#pragma unroll
    for (int n = 0; n < 2; ++n) {
        const int e = 32 * wv + 16 * n + r15;
#pragma unroll
        for (int ks = 0; ks < 4; ++ks) {
            const int cw = (4 * ks + hi) ^ (e & 15);
            bfr[n][ks] = *(const bf16x8*)&cL[e][cw * 8];
        }
    }

    stageq(0, 0);
    for (int t = 0; t < 16; ++t) {
        __syncthreads();
        if (t + 1 < 16) stageq(t + 1, (t + 1) & 1);
        const int buf = t & 1;

        f32x4 acc[2][2];
#pragma unroll
        for (int m = 0; m < 2; ++m)
#pragma unroll
            for (int n = 0; n < 2; ++n) acc[m][n] = (f32x4){0.f, 0.f, 0.f, 0.f};

#pragma unroll
        for (int ks = 0; ks < 4; ++ks) {
            bf16x8 af[2];
#pragma unroll
            for (int m = 0; m < 2; ++m) {
                const int s = 16 * m + r15;
                const int cw = (4 * ks + hi) ^ (s & 15);
                af[m] = *(const bf16x8*)&qL[buf][s][cw * 8];
            }
#pragma unroll
            for (int m = 0; m < 2; ++m)
#pragma unroll
                for (int n = 0; n < 2; ++n)
                    acc[m][n] = __builtin_amdgcn_mfma_f32_16x16x32_bf16(
                        af[m], bfr[n][ks], acc[m][n], 0, 0, 0);
        }

        // normalize + write
#pragma unroll
        for (int m = 0; m < 2; ++m) {
            const int sl0 = 16 * m + 4 * hi;
            const float i0 = 1.f / qd[buf][sl0];
            const float i1 = 1.f / qd[buf][sl0 + 1];
            const float i2 = 1.f / qd[buf][sl0 + 2];
            const float i3 = 1.f / qd[buf][sl0 + 3];
            const int srow = s_blk + t * 32 + sl0;
            float* ob = out + ((size_t)b * NS + srow) * HD + (size_t)h * ND;
#pragma unroll
            for (int n = 0; n < 2; ++n) {
                const int e = 32 * wv + 16 * n + r15;
                ob[0 * HD + e] = acc[m][n][0] * i0;
                ob[1 * HD + e] = acc[m][n][1] * i1;
                ob[2 * HD + e] = acc[m][n][2] * i2;
                ob[3 * HD + e] = acc[m][n][3] * i3;
            }
        }
    }
}

// ---------------------------------------------------------------------------
extern "C" void kernel_launch(void* const* d_in, const int* in_sizes, int n_in,
                              void* d_out, int out_size, void* d_ws, size_t ws_size,
                              hipStream_t stream) {
    (void)in_sizes; (void)n_in; (void)out_size;
    const float* q = (const float*)d_in[0];
    const float* k = (const float*)d_in[1];
    const float* v = (const float*)d_in[2];
    float* out = (float*)d_out;

    auto need = [](size_t nc) -> size_t {
        return 4ull * ((size_t)BH * nc * ND * ND + (size_t)BH * nc * ND) +
               2ull * (size_t)BH * ND * ND;
    };
    const int nc = (ws_size >= need(4)) ? 4 : (ws_size >= need(2)) ? 2 : 1;

    float* pctx_t = (float*)d_ws;
    float* pden   = pctx_t + (size_t)BH * nc * ND * ND;
    unsigned short* ctx_t = (unsigned short*)(pden + (size_t)BH * nc * ND);

    if (nc == 4)
        ctx_mfma<4><<<BH * 4, 256, 0, stream>>>(k, v, pctx_t, pden);
    else if (nc == 2)
        ctx_mfma<2><<<BH * 2, 256, 0, stream>>>(k, v, pctx_t, pden);
    else
        ctx_mfma<1><<<BH * 1, 256, 0, stream>>>(k, v, pctx_t, pden);

    ctx_combine<<<(BH * ND * ND / 2) / 256, 256, 0, stream>>>(pctx_t, pden, ctx_t, nc);

    out_mfma<<<BH * 8, 256, 0, stream>>>(q, ctx_t, out);
}